// Round 1
// baseline (104.822 us; speedup 1.0000x reference)
//
#include <hip/hip_runtime.h>
#include <hip/hip_bf16.h>

// Problem: x[32,64,224,224] f32 -> BN(inference affine)+ReLU -> 1x1 conv (64->32)
//          -> 2x2 avgpool s2 -> out[32,32,112,112] f32.
// Algebra: conv (linear over C) commutes with avgpool (linear over space),
//          so: relu-affine -> pool 2x2 -> 32x64 matvec. ReLU must stay before pool.
// Streaming: each x element is used exactly once -> memory-bound, floor ~73us.

#define EPS_BN 1e-5f

constexpr int N_   = 32;
constexpr int CIN  = 64;
constexpr int COUT = 32;
constexpr int H_   = 224;
constexpr int W_   = 224;
constexpr int H2   = 112;
constexpr int W2   = 112;
constexpr int PIX  = N_ * H2 * W2;       // 401408 pooled pixels
constexpr int BLK  = 256;

// d_ws layout (floats): [0..63]=scale, [64..127]=bias, [128..128+2048)=wT[c][o]
__global__ void prep_kernel(const float* __restrict__ conv_w,
                            const float* __restrict__ gamma,
                            const float* __restrict__ beta,
                            const float* __restrict__ rmean,
                            const float* __restrict__ rvar,
                            float* __restrict__ ws) {
    int c = threadIdx.x;            // 64 threads, one per input channel
    if (c < CIN) {
        float s = gamma[c] * rsqrtf(rvar[c] + EPS_BN);
        float b = beta[c] - rmean[c] * s;
        ws[c]        = s;
        ws[CIN + c]  = b;
        // transpose conv_w [o][c] -> wT [c][o] so per-c weight rows are contiguous
        for (int o = 0; o < COUT; ++o)
            ws[2 * CIN + c * COUT + o] = conv_w[o * CIN + c];
    }
}

__global__ __launch_bounds__(BLK) void fused_kernel(const float* __restrict__ x,
                                                    const float* __restrict__ ws,
                                                    float* __restrict__ out) {
    const float* __restrict__ sc = ws;            // [64]
    const float* __restrict__ bi = ws + CIN;      // [64]
    const float* __restrict__ wT = ws + 2 * CIN;  // [64][32]

    int i = blockIdx.x * BLK + threadIdx.x;       // pooled pixel id, PIX % BLK == 0
    int n  = i / (H2 * W2);
    int r  = i - n * (H2 * W2);
    int h2 = r / W2;
    int w2 = r - h2 * W2;

    // base of the 2x2 window for channel 0
    const float* __restrict__ px =
        x + ((size_t)n * CIN * H_ + (size_t)(2 * h2)) * W_ + (size_t)(2 * w2);

    float acc[COUT];
#pragma unroll
    for (int o = 0; o < COUT; ++o) acc[o] = 0.0f;

#pragma unroll
    for (int c = 0; c < CIN; ++c) {
        const float* p = px + (size_t)c * (H_ * W_);
        float2 r0 = *reinterpret_cast<const float2*>(p);
        float2 r1 = *reinterpret_cast<const float2*>(p + W_);
        float s = sc[c];   // uniform address -> s_load, broadcast
        float b = bi[c];
        float y = fmaxf(fmaf(r0.x, s, b), 0.0f)
                + fmaxf(fmaf(r0.y, s, b), 0.0f)
                + fmaxf(fmaf(r1.x, s, b), 0.0f)
                + fmaxf(fmaf(r1.y, s, b), 0.0f);
        y *= 0.25f;        // 2x2 mean
#pragma unroll
        for (int o = 0; o < COUT; ++o)
            acc[o] = fmaf(wT[c * COUT + o], y, acc[o]);  // wT uniform -> SGPR operand
    }

    // out[((n*COUT + o)*H2 + h2)*W2 + w2]
    float* __restrict__ po = out + ((size_t)n * COUT * H2 + (size_t)h2) * W2 + (size_t)w2;
#pragma unroll
    for (int o = 0; o < COUT; ++o)
        po[(size_t)o * (H2 * W2)] = acc[o];
}

extern "C" void kernel_launch(void* const* d_in, const int* in_sizes, int n_in,
                              void* d_out, int out_size, void* d_ws, size_t ws_size,
                              hipStream_t stream) {
    const float* x      = (const float*)d_in[0];
    const float* conv_w = (const float*)d_in[1];
    const float* gamma  = (const float*)d_in[2];
    const float* beta   = (const float*)d_in[3];
    const float* rmean  = (const float*)d_in[4];
    const float* rvar   = (const float*)d_in[5];
    float* out = (float*)d_out;
    float* ws  = (float*)d_ws;

    prep_kernel<<<1, 64, 0, stream>>>(conv_w, gamma, beta, rmean, rvar, ws);
    fused_kernel<<<PIX / BLK, BLK, 0, stream>>>(x, ws, out);
}